// Round 1
// baseline (748.563 us; speedup 1.0000x reference)
//
#include <hip/hip_runtime.h>
#include <hip/hip_bf16.h>
#include <cmath>

// Problem constants (match reference)
constexpr int BB_ = 2;
constexpr int T_  = 1024;
constexpr int E_  = 1024;
constexpr int H_  = 8;
constexpr int HD_ = 128;
constexpr int WS_ = 64;
constexpr float TAU_   = 10.0f;
constexpr float SCALE_ = 0.08838834764831843f;  // 1/sqrt(128)

// ---------------------------------------------------------------------------
// Kernel 1: exact stable argsort via rank counting (T=1024 per batch).
// rank[t] = #{u : c[u] < c[t]  or (c[u]==c[t] and u<t)}  == stable sort rank.
// Writes sort_idx (rank -> original t), c_s (sorted coords), depot (rank of t=0).
// ---------------------------------------------------------------------------
__global__ __launch_bounds__(256) void sort_rank_kernel(
    const float* __restrict__ coord, int* __restrict__ sidx,
    float* __restrict__ c_s, int* __restrict__ depot) {
  __shared__ float c[T_];
  const int b = blockIdx.x;
  const float* cb = coord + (size_t)b * T_;
  for (int i = threadIdx.x; i < T_; i += 256) c[i] = cb[i];
  __syncthreads();
  for (int t = threadIdx.x; t < T_; t += 256) {
    const float ct = c[t];
    int rank = 0;
    #pragma unroll 8
    for (int u = 0; u < T_; ++u) {
      const float cu = c[u];
      rank += (cu < ct) || (cu == ct && u < t);
    }
    sidx[b * T_ + rank] = t;
    c_s[b * T_ + rank] = ct;
    if (t == 0) depot[b] = rank;
  }
}

// ---------------------------------------------------------------------------
// Kernel 2: fp32 GEMM  C[m,n] = sum_k A[m,k] * W[n,k] + bias[n]
//   GATHER: A row m reads global row (b*T + sidx[m])  (fused h -> h_s gather)
//   SCATTER: C row m stores to global row (b*T + sidx[m]) (fused un-sort)
//   blockIdx.z selects among up to 3 weight/bias/output triples (QKV fusion).
// Tiling: BMv x 128, BK=16, 256 threads, each (BMv/16) x 8 accumulators.
// ---------------------------------------------------------------------------
struct GemmArgs {
  const float* W[3];
  const float* bias[3];
  float* C[3];
};

constexpr int BKT_ = 16;

template <int BMv, int GATHER, int SCATTER>
__global__ __launch_bounds__(256) void gemm_kernel(
    GemmArgs args, const float* __restrict__ A, const int* __restrict__ sidx) {
  constexpr int TM = BMv / 16;              // per-thread rows
  constexpr int NF4A = (BMv * BKT_) / (4 * 256);  // float4 A-loads per thread
  const float* __restrict__ W    = args.W[blockIdx.z];
  const float* __restrict__ bias = args.bias[blockIdx.z];
  float* __restrict__ C          = args.C[blockIdx.z];

  __shared__ float As[BKT_][BMv];
  __shared__ float Bs[BKT_][128];

  const int tid = threadIdx.x;
  const int tx = tid & 15, ty = tid >> 4;
  const int m0 = blockIdx.y * BMv;
  const int n0 = blockIdx.x * 128;

  float acc[TM][8];
  #pragma unroll
  for (int i = 0; i < TM; ++i)
    #pragma unroll
    for (int j = 0; j < 8; ++j) acc[i][j] = 0.f;

  for (int k0 = 0; k0 < E_; k0 += BKT_) {
    #pragma unroll
    for (int i = 0; i < NF4A; ++i) {
      const int idx = tid + 256 * i;         // over BMv*4 float4s
      const int r = idx >> 2, c4 = idx & 3;
      const int gr = m0 + r;
      const int grow = GATHER ? ((gr & ~(T_ - 1)) + sidx[gr]) : gr;
      const float4 v = *(const float4*)(A + (size_t)grow * E_ + k0 + c4 * 4);
      As[c4 * 4 + 0][r] = v.x; As[c4 * 4 + 1][r] = v.y;
      As[c4 * 4 + 2][r] = v.z; As[c4 * 4 + 3][r] = v.w;
    }
    #pragma unroll
    for (int i = 0; i < 2; ++i) {            // 128 rows x 4 float4
      const int idx = tid + 256 * i;
      const int r = idx >> 2, c4 = idx & 3;
      const float4 v = *(const float4*)(W + (size_t)(n0 + r) * E_ + k0 + c4 * 4);
      Bs[c4 * 4 + 0][r] = v.x; Bs[c4 * 4 + 1][r] = v.y;
      Bs[c4 * 4 + 2][r] = v.z; Bs[c4 * 4 + 3][r] = v.w;
    }
    __syncthreads();
    #pragma unroll
    for (int kk = 0; kk < BKT_; ++kk) {
      float a[TM], bb[8];
      #pragma unroll
      for (int i = 0; i < TM / 4; ++i)
        *(float4*)&a[i * 4] = *(const float4*)&As[kk][ty * TM + i * 4];
      *(float4*)&bb[0] = *(const float4*)&Bs[kk][tx * 8];
      *(float4*)&bb[4] = *(const float4*)&Bs[kk][tx * 8 + 4];
      #pragma unroll
      for (int i = 0; i < TM; ++i)
        #pragma unroll
        for (int j = 0; j < 8; ++j) acc[i][j] = fmaf(a[i], bb[j], acc[i][j]);
    }
    __syncthreads();
  }

  #pragma unroll
  for (int i = 0; i < TM; ++i) {
    const int gr = m0 + ty * TM + i;
    const int orow = SCATTER ? ((gr & ~(T_ - 1)) + sidx[gr]) : gr;
    float* crow = C + (size_t)orow * E_ + n0 + tx * 8;
    #pragma unroll
    for (int j = 0; j < 8; ++j) crow[j] = acc[i][j] + bias[n0 + tx * 8 + j];
  }
}

// ---------------------------------------------------------------------------
// Kernel 3: local sliding-window attention.
// One block per (b, h, tile of QT=16 queries). Window of query t:
// keys [st, st+64), st = min(max(t-32,0), T-64), plus forced depot column
// (masked out if depot already inside the window).
// K-window staged in LDS (reused 16x65 times); V read coalesced from L2.
// ---------------------------------------------------------------------------
constexpr int QT_ = 16;
constexpr int MAXR_ = 80;   // max staged key rows: (QT-1)+64 window span + depot
constexpr int RPAD_ = 132;  // row stride (floats), 16B-aligned, breaks 128 stride

__global__ __launch_bounds__(256) void attn_local_kernel(
    const float* __restrict__ Q, const float* __restrict__ K,
    const float* __restrict__ V, const float* __restrict__ c_s,
    const int* __restrict__ depot, float* __restrict__ ctx) {
  __shared__ float Ks[MAXR_][RPAD_];   // 42240 B
  __shared__ float Qs[QT_][RPAD_];     //  8448 B
  __shared__ float sc[QT_][68];        //  4352 B (scores -> attn, in place)
  __shared__ float cw[MAXR_];
  __shared__ float cq[QT_];

  const int tid = threadIdx.x;
  const int ntq = T_ / QT_;                  // 64
  const int tq = blockIdx.x % ntq;
  const int bh = blockIdx.x / ntq;
  const int h = bh % H_, b = bh / H_;
  const int t0 = tq * QT_;
  const int dep = depot[b];

  const int smin = min(max(t0 - WS_ / 2, 0), T_ - WS_);
  const int smax = min(max(t0 + QT_ - 1 - WS_ / 2, 0), T_ - WS_);
  const int nk = smax + WS_ - smin;          // <= 79
  const int nrow = nk + 1;                   // + depot slot at index nk

  const size_t baseBH = ((size_t)b * T_) * E_ + (size_t)h * HD_;

  // stage K rows (window + depot) as float4
  const int nf4 = nrow * (HD_ / 4);
  for (int i4 = tid; i4 < nf4; i4 += 256) {
    const int r = i4 >> 5, c4 = i4 & 31;
    const int key = (r < nk) ? (smin + r) : dep;
    const float4 kv = *(const float4*)(K + baseBH + (size_t)key * E_ + c4 * 4);
    *(float4*)&Ks[r][c4 * 4] = kv;
  }
  for (int r = tid; r < nrow; r += 256) {
    const int key = (r < nk) ? (smin + r) : dep;
    cw[r] = c_s[b * T_ + key];
  }
  // stage Q tile
  for (int i4 = tid; i4 < QT_ * (HD_ / 4); i4 += 256) {
    const int r = i4 >> 5, c4 = i4 & 31;
    const float4 qv = *(const float4*)(Q + baseBH + (size_t)(t0 + r) * E_ + c4 * 4);
    *(float4*)&Qs[r][c4 * 4] = qv;
  }
  if (tid < QT_) cq[tid] = c_s[b * T_ + t0 + tid];
  __syncthreads();

  // scores: QT*65 = 1040 (query, key-col) pairs
  for (int p = tid; p < QT_ * 65; p += 256) {
    const int q = p / 65;
    const int j = p - q * 65;
    const int t = t0 + q;
    const int st = min(max(t - WS_ / 2, 0), T_ - WS_);
    const int base = st - smin;
    const bool isdep = (j == 64);
    const int widx = isdep ? nk : (base + j);
    const bool masked = isdep && ((unsigned)(dep - st) < (unsigned)WS_);
    float s;
    if (masked) {
      s = -3.0e38f;
    } else {
      const float* kr = &Ks[widx][0];
      const float* qr = &Qs[q][0];
      float dot = 0.f;
      #pragma unroll
      for (int d4 = 0; d4 < HD_ / 4; ++d4) {
        const float4 kv = *(const float4*)(kr + d4 * 4);
        const float4 qv = *(const float4*)(qr + d4 * 4);
        dot = fmaf(kv.x, qv.x, dot); dot = fmaf(kv.y, qv.y, dot);
        dot = fmaf(kv.z, qv.z, dot); dot = fmaf(kv.w, qv.w, dot);
      }
      const float dd = cw[widx] - cq[q];
      s = dot * SCALE_ - dd * dd * (1.0f / TAU_);
    }
    sc[q][j] = s;
  }
  __syncthreads();

  // softmax: wave w handles queries w*4 .. w*4+3; lane j holds col j (<64),
  // depot col 64 handled scalar.
  const int wv = tid >> 6, lane = tid & 63;
  for (int qi = 0; qi < QT_ / 4; ++qi) {
    const int q = wv * (QT_ / 4) + qi;
    const float v = sc[q][lane];
    float m = v;
    #pragma unroll
    for (int o = 32; o > 0; o >>= 1) m = fmaxf(m, __shfl_xor(m, o));
    const float sdep = sc[q][64];
    m = fmaxf(m, sdep);
    const float e = expf(v - m);
    float sum = e;
    #pragma unroll
    for (int o = 32; o > 0; o >>= 1) sum += __shfl_xor(sum, o);
    const float edep = expf(sdep - m);
    sum += edep;
    const float inv = 1.0f / sum;
    sc[q][lane] = e * inv;
    if (lane == 0) sc[q][64] = edep * inv;
  }
  __syncthreads();

  // ctx: QT*HD = 2048 (q, d) pairs; V read coalesced from global (L2-hot).
  for (int p = tid; p < QT_ * HD_; p += 256) {
    const int q = p >> 7, d = p & 127;
    const int t = t0 + q;
    const int st = min(max(t - WS_ / 2, 0), T_ - WS_);
    const float* vbase = V + baseBH + d;
    float acc = 0.f;
    #pragma unroll 8
    for (int j = 0; j < WS_; ++j) {
      acc = fmaf(sc[q][j], vbase[(size_t)(st + j) * E_], acc);
    }
    acc = fmaf(sc[q][64], vbase[(size_t)dep * E_], acc);
    ctx[baseBH + (size_t)t * E_ + d] = acc;
  }
}

// ---------------------------------------------------------------------------
// Kernel 4: depot attends to the full sequence. One block per (b, h).
// Overwrites ctx row at (b, depot) — output GEMM then produces the final row.
// ---------------------------------------------------------------------------
__global__ __launch_bounds__(256) void attn_depot_kernel(
    const float* __restrict__ Q, const float* __restrict__ K,
    const float* __restrict__ V, const float* __restrict__ c_s,
    const int* __restrict__ depot, float* __restrict__ ctx) {
  __shared__ float qd[HD_];
  __shared__ float sc[T_];
  __shared__ float red[4];
  __shared__ float par[2][HD_];

  const int h = blockIdx.x % H_, b = blockIdx.x / H_;
  const int tid = threadIdx.x;
  const int wv = tid >> 6, lane = tid & 63;
  const int dep = depot[b];
  const size_t baseBH = ((size_t)b * T_) * E_ + (size_t)h * HD_;

  if (tid < HD_) qd[tid] = Q[baseBH + (size_t)dep * E_ + tid];
  __syncthreads();
  const float cdep = c_s[b * T_ + dep];

  // scores: one wave per key, lanes over d (coalesced K reads)
  for (int k = wv; k < T_; k += 4) {
    const float* krow = K + baseBH + (size_t)k * E_;
    float part = fmaf(qd[lane], krow[lane], qd[lane + 64] * krow[lane + 64]);
    #pragma unroll
    for (int o = 32; o > 0; o >>= 1) part += __shfl_xor(part, o);
    if (lane == 0) {
      const float dd = c_s[b * T_ + k] - cdep;
      sc[k] = part * SCALE_ - dd * dd * (1.0f / TAU_);
    }
  }
  __syncthreads();

  // block softmax over T
  float lm = -3.0e38f;
  for (int k = tid; k < T_; k += 256) lm = fmaxf(lm, sc[k]);
  #pragma unroll
  for (int o = 32; o > 0; o >>= 1) lm = fmaxf(lm, __shfl_xor(lm, o));
  if (lane == 0) red[wv] = lm;
  __syncthreads();
  const float M = fmaxf(fmaxf(red[0], red[1]), fmaxf(red[2], red[3]));
  __syncthreads();
  float ls = 0.f;
  for (int k = tid; k < T_; k += 256) {
    const float e = expf(sc[k] - M);
    sc[k] = e;
    ls += e;
  }
  #pragma unroll
  for (int o = 32; o > 0; o >>= 1) ls += __shfl_xor(ls, o);
  if (lane == 0) red[wv] = ls;
  __syncthreads();
  const float inv = 1.0f / (red[0] + red[1] + red[2] + red[3]);
  __syncthreads();

  // ctx: 2 key-halves x 128 dims
  const int kg = tid >> 7, d = tid & 127;
  const float* vbase = V + baseBH + d;
  float acc = 0.f;
  #pragma unroll 8
  for (int k = kg * 512; k < kg * 512 + 512; ++k) {
    acc = fmaf(sc[k], vbase[(size_t)k * E_], acc);
  }
  par[kg][d] = acc * inv;
  __syncthreads();
  if (tid < HD_) ctx[baseBH + (size_t)dep * E_ + tid] = par[0][tid] + par[1][tid];
}

// ---------------------------------------------------------------------------
extern "C" void kernel_launch(void* const* d_in, const int* in_sizes, int n_in,
                              void* d_out, int out_size, void* d_ws, size_t ws_size,
                              hipStream_t stream) {
  const float* h     = (const float*)d_in[0];
  const float* coord = (const float*)d_in[1];
  const float* Wq    = (const float*)d_in[2];
  const float* Wqb   = (const float*)d_in[3];
  const float* Wk    = (const float*)d_in[4];
  const float* Wkb   = (const float*)d_in[5];
  const float* Wv    = (const float*)d_in[6];
  const float* Wvb   = (const float*)d_in[7];
  const float* Wo    = (const float*)d_in[8];
  const float* Wob   = (const float*)d_in[9];
  float* out = (float*)d_out;

  char* ws = (char*)d_ws;
  const size_t MAT = (size_t)BB_ * T_ * E_ * sizeof(float);  // 8 MB
  float* Qb  = (float*)(ws + 0 * MAT);
  float* Kb  = (float*)(ws + 1 * MAT);
  float* Vb  = (float*)(ws + 2 * MAT);
  float* CTX = (float*)(ws + 3 * MAT);
  float* c_s = (float*)(ws + 4 * MAT);
  int* sidx  = (int*)(ws + 4 * MAT + (size_t)BB_ * T_ * 4);
  int* depo  = (int*)(ws + 4 * MAT + (size_t)2 * BB_ * T_ * 4);

  // 1. stable sort by coordinate (rank counting)
  sort_rank_kernel<<<BB_, 256, 0, stream>>>(coord, sidx, c_s, depo);

  // 2. fused gather + QKV projections (grid.z selects Q/K/V)
  GemmArgs qa;
  qa.W[0] = Wq;  qa.W[1] = Wk;  qa.W[2] = Wv;
  qa.bias[0] = Wqb; qa.bias[1] = Wkb; qa.bias[2] = Wvb;
  qa.C[0] = Qb;  qa.C[1] = Kb;  qa.C[2] = Vb;
  gemm_kernel<128, 1, 0><<<dim3(E_ / 128, (BB_ * T_) / 128, 3), 256, 0, stream>>>(
      qa, h, sidx);

  // 3. sliding-window attention -> ctx
  attn_local_kernel<<<BB_ * H_ * (T_ / QT_), 256, 0, stream>>>(
      Qb, Kb, Vb, c_s, depo, CTX);

  // 4. depot full attention (overwrites ctx depot rows)
  attn_depot_kernel<<<BB_ * H_, 256, 0, stream>>>(Qb, Kb, Vb, c_s, depo, CTX);

  // 5. output projection with fused un-sort scatter (BM=64 -> 256 blocks)
  GemmArgs oa;
  oa.W[0] = Wo;  oa.W[1] = Wo;  oa.W[2] = Wo;
  oa.bias[0] = Wob; oa.bias[1] = Wob; oa.bias[2] = Wob;
  oa.C[0] = out; oa.C[1] = out; oa.C[2] = out;
  gemm_kernel<64, 0, 1><<<dim3(E_ / 128, (BB_ * T_) / 64, 1), 256, 0, stream>>>(
      oa, CTX, sidx);
}

// Round 3
// 532.224 us; speedup vs baseline: 1.4065x; 1.4065x over previous
//
#include <hip/hip_runtime.h>
#include <hip/hip_bf16.h>
#include <cmath>

// Problem constants (match reference)
constexpr int BB_ = 2;
constexpr int T_  = 1024;
constexpr int E_  = 1024;
constexpr int H_  = 8;
constexpr int HD_ = 128;
constexpr int WS_ = 64;
constexpr float TAU_   = 10.0f;
constexpr float SCALE_ = 0.08838834764831843f;  // 1/sqrt(128)

typedef __attribute__((ext_vector_type(8))) short short8;
typedef __attribute__((ext_vector_type(4))) short shortx4;
typedef __attribute__((ext_vector_type(4))) float floatx4;

// Split fp32 -> bf16 hi + bf16 lo (RNE both). x ~= hi + lo to ~2^-17 rel.
struct BfPair { short hi, lo; };
__device__ inline BfPair f2bf_pair(float x) {
  union { float f; unsigned u; } a; a.f = x;
  unsigned rh = (a.u + 0x7FFFu + ((a.u >> 16) & 1u)) >> 16;
  union { unsigned u; float f; } hf; hf.u = rh << 16;
  union { float f; unsigned u; } b; b.f = x - hf.f;
  unsigned rl = (b.u + 0x7FFFu + ((b.u >> 16) & 1u)) >> 16;
  BfPair r; r.hi = (short)rh; r.lo = (short)rl; return r;
}

// ---------------------------------------------------------------------------
// Kernel 1: exact stable argsort via rank counting (T=1024 per batch).
// ---------------------------------------------------------------------------
__global__ __launch_bounds__(256) void sort_rank_kernel(
    const float* __restrict__ coord, int* __restrict__ sidx,
    float* __restrict__ c_s, int* __restrict__ depot) {
  __shared__ float c[T_];
  const int b = blockIdx.x;
  const float* cb = coord + (size_t)b * T_;
  for (int i = threadIdx.x; i < T_; i += 256) c[i] = cb[i];
  __syncthreads();
  for (int t = threadIdx.x; t < T_; t += 256) {
    const float ct = c[t];
    int rank = 0;
    #pragma unroll 8
    for (int u = 0; u < T_; ++u) {
      const float cu = c[u];
      rank += (cu < ct) || (cu == ct && u < t);
    }
    sidx[b * T_ + rank] = t;
    c_s[b * T_ + rank] = ct;
    if (t == 0) depot[b] = rank;
  }
}

// ---------------------------------------------------------------------------
// Kernel 2a: gather (h -> h_s) fused with fp32 -> bf16 hi/lo split.
// One block per sorted row; 256 threads x float4.
// ---------------------------------------------------------------------------
__global__ __launch_bounds__(256) void convert_gather_h(
    const float* __restrict__ h, const int* __restrict__ sidx,
    short* __restrict__ Ahi, short* __restrict__ Alo) {
  const int gr = blockIdx.x;  // 0..B*T-1 (sorted domain)
  const int srow = (gr & ~(T_ - 1)) + sidx[gr];
  const float4 v = *(const float4*)(h + (size_t)srow * E_ + threadIdx.x * 4);
  shortx4 hv, lv;
  BfPair p0 = f2bf_pair(v.x), p1 = f2bf_pair(v.y);
  BfPair p2 = f2bf_pair(v.z), p3 = f2bf_pair(v.w);
  hv.x = p0.hi; hv.y = p1.hi; hv.z = p2.hi; hv.w = p3.hi;
  lv.x = p0.lo; lv.y = p1.lo; lv.z = p2.lo; lv.w = p3.lo;
  const size_t o = (size_t)gr * E_ + threadIdx.x * 4;
  *(shortx4*)(Ahi + o) = hv;
  *(shortx4*)(Alo + o) = lv;
}

// ---------------------------------------------------------------------------
// Kernel 2b: weight fp32 -> bf16 hi/lo split (4 matrices via grid.z).
// ---------------------------------------------------------------------------
struct WConv {
  const float* src[4];
  short* hi[4];
  short* lo[4];
};

__global__ __launch_bounds__(256) void convert_w_kernel(WConv a) {
  const int z = blockIdx.z;
  const size_t idx = ((size_t)blockIdx.x * 256 + threadIdx.x) * 4;
  const float4 v = *(const float4*)(a.src[z] + idx);
  shortx4 hv, lv;
  BfPair p0 = f2bf_pair(v.x), p1 = f2bf_pair(v.y);
  BfPair p2 = f2bf_pair(v.z), p3 = f2bf_pair(v.w);
  hv.x = p0.hi; hv.y = p1.hi; hv.z = p2.hi; hv.w = p3.hi;
  lv.x = p0.lo; lv.y = p1.lo; lv.z = p2.lo; lv.w = p3.lo;
  *(shortx4*)(a.hi[z] + idx) = hv;
  *(shortx4*)(a.lo[z] + idx) = lv;
}

// ---------------------------------------------------------------------------
// Kernel 3: bf16x3 split-precision MFMA GEMM.
//   C[m,n] = sum_k (Ahi+Alo)[m,k] * (Whi+Wlo)[n,k] + bias[n]
//          ~= Ahi*Whi + Ahi*Wlo + Alo*Whi   (lo*lo dropped, ~2^-18 rel)
// Tile BM x 128, BK=32, 256 threads = 4 waves in 2x2, wave tile WM x 64.
// 16x16x32 bf16 MFMA; A-frag: A[m=lane&15][k=(lane>>4)*8+j];
// C/D: col=lane&15, row=(lane>>4)*4+reg  [m89-verified].
// LDS rows padded to 56 shorts (112 B: 16B-aligned, 2-way bank max = free).
// SCATTER: store row m to (batch_base + sidx[m])  (fused un-sort).
// ---------------------------------------------------------------------------
struct GemmArgs {
  const short* Whi[3];
  const short* Wlo[3];
  const float* bias[3];
  float* C[3];
};

constexpr int LP_ = 56;  // padded LDS row stride (shorts)

template <int BM, int WM, int SCATTER>
__global__ __launch_bounds__(256, 2) void gemm_bf16x3(
    GemmArgs args, const short* __restrict__ Ahi, const short* __restrict__ Alo,
    const int* __restrict__ sidx) {
  constexpr int TMI = WM / 16;
  const short* __restrict__ Whi = args.Whi[blockIdx.z];
  const short* __restrict__ Wlo = args.Wlo[blockIdx.z];
  const float* __restrict__ bias = args.bias[blockIdx.z];
  float* __restrict__ C = args.C[blockIdx.z];

  __shared__ short As_hi[BM][LP_], As_lo[BM][LP_];
  __shared__ short Bs_hi[128][LP_], Bs_lo[128][LP_];

  const int tid = threadIdx.x;
  const int wv = tid >> 6, lane = tid & 63;
  const int kq = lane >> 4, ln15 = lane & 15;
  const int wm0 = (wv >> 1) * WM, wn0 = (wv & 1) * 64;
  const int m0 = blockIdx.y * BM, n0 = blockIdx.x * 128;

  floatx4 acc[TMI][4];
  #pragma unroll
  for (int i = 0; i < TMI; ++i)
    #pragma unroll
    for (int j = 0; j < 4; ++j) acc[i][j] = (floatx4){0.f, 0.f, 0.f, 0.f};

  for (int k0 = 0; k0 < E_; k0 += 32) {
    // stage A tile (BM x 32 hi+lo)
    #pragma unroll
    for (int i = 0; i < BM * 4 / 256; ++i) {
      const int idx = tid + 256 * i;
      const int r = idx >> 2, c = idx & 3;
      const size_t g = (size_t)(m0 + r) * E_ + k0 + c * 8;
      *(short8*)&As_hi[r][c * 8] = *(const short8*)(Ahi + g);
      *(short8*)&As_lo[r][c * 8] = *(const short8*)(Alo + g);
    }
    // stage B tile (128 x 32 hi+lo)
    #pragma unroll
    for (int i = 0; i < 2; ++i) {
      const int idx = tid + 256 * i;
      const int r = idx >> 2, c = idx & 3;
      const size_t g = (size_t)(n0 + r) * E_ + k0 + c * 8;
      *(short8*)&Bs_hi[r][c * 8] = *(const short8*)(Whi + g);
      *(short8*)&Bs_lo[r][c * 8] = *(const short8*)(Wlo + g);
    }
    __syncthreads();

    short8 ah[TMI], al[TMI], bh[4], bl[4];
    #pragma unroll
    for (int mi = 0; mi < TMI; ++mi) {
      ah[mi] = *(const short8*)&As_hi[wm0 + mi * 16 + ln15][kq * 8];
      al[mi] = *(const short8*)&As_lo[wm0 + mi * 16 + ln15][kq * 8];
    }
    #pragma unroll
    for (int ni = 0; ni < 4; ++ni) {
      bh[ni] = *(const short8*)&Bs_hi[wn0 + ni * 16 + ln15][kq * 8];
      bl[ni] = *(const short8*)&Bs_lo[wn0 + ni * 16 + ln15][kq * 8];
    }
    #pragma unroll
    for (int mi = 0; mi < TMI; ++mi)
      #pragma unroll
      for (int ni = 0; ni < 4; ++ni) {
        acc[mi][ni] = __builtin_amdgcn_mfma_f32_16x16x32_bf16(
            ah[mi], bh[ni], acc[mi][ni], 0, 0, 0);
        acc[mi][ni] = __builtin_amdgcn_mfma_f32_16x16x32_bf16(
            ah[mi], bl[ni], acc[mi][ni], 0, 0, 0);
        acc[mi][ni] = __builtin_amdgcn_mfma_f32_16x16x32_bf16(
            al[mi], bh[ni], acc[mi][ni], 0, 0, 0);
      }
    __syncthreads();
  }

  // epilogue: bias + (optional) un-sort scatter
  #pragma unroll
  for (int ni = 0; ni < 4; ++ni) {
    const int col = n0 + wn0 + ni * 16 + ln15;
    const float bv = bias[col];
    #pragma unroll
    for (int mi = 0; mi < TMI; ++mi) {
      #pragma unroll
      for (int r = 0; r < 4; ++r) {
        const int m = m0 + wm0 + mi * 16 + kq * 4 + r;
        const int orow = SCATTER ? ((m & ~(T_ - 1)) + sidx[m]) : m;
        C[(size_t)orow * E_ + col] = acc[mi][ni][r] + bv;
      }
    }
  }
}

// ---------------------------------------------------------------------------
// Kernel 4: local sliding-window attention (fp32 compute, bf16-split ctx out).
// ---------------------------------------------------------------------------
constexpr int QT_ = 16;
constexpr int MAXR_ = 80;
constexpr int RPAD_ = 132;

__global__ __launch_bounds__(256) void attn_local_kernel(
    const float* __restrict__ Q, const float* __restrict__ K,
    const float* __restrict__ V, const float* __restrict__ c_s,
    const int* __restrict__ depot, short* __restrict__ CTXhi,
    short* __restrict__ CTXlo) {
  __shared__ float Ks[MAXR_][RPAD_];
  __shared__ float Qs[QT_][RPAD_];
  __shared__ float sc[QT_][68];
  __shared__ float cw[MAXR_];
  __shared__ float cq[QT_];

  const int tid = threadIdx.x;
  const int ntq = T_ / QT_;
  const int tq = blockIdx.x % ntq;
  const int bh = blockIdx.x / ntq;
  const int h = bh % H_, b = bh / H_;
  const int t0 = tq * QT_;
  const int dep = depot[b];

  const int smin = min(max(t0 - WS_ / 2, 0), T_ - WS_);
  const int smax = min(max(t0 + QT_ - 1 - WS_ / 2, 0), T_ - WS_);
  const int nk = smax + WS_ - smin;
  const int nrow = nk + 1;

  const size_t baseBH = ((size_t)b * T_) * E_ + (size_t)h * HD_;

  const int nf4 = nrow * (HD_ / 4);
  for (int i4 = tid; i4 < nf4; i4 += 256) {
    const int r = i4 >> 5, c4 = i4 & 31;
    const int key = (r < nk) ? (smin + r) : dep;
    const float4 kv = *(const float4*)(K + baseBH + (size_t)key * E_ + c4 * 4);
    *(float4*)&Ks[r][c4 * 4] = kv;
  }
  for (int r = tid; r < nrow; r += 256) {
    const int key = (r < nk) ? (smin + r) : dep;
    cw[r] = c_s[b * T_ + key];
  }
  for (int i4 = tid; i4 < QT_ * (HD_ / 4); i4 += 256) {
    const int r = i4 >> 5, c4 = i4 & 31;
    const float4 qv = *(const float4*)(Q + baseBH + (size_t)(t0 + r) * E_ + c4 * 4);
    *(float4*)&Qs[r][c4 * 4] = qv;
  }
  if (tid < QT_) cq[tid] = c_s[b * T_ + t0 + tid];
  __syncthreads();

  for (int p = tid; p < QT_ * 65; p += 256) {
    const int q = p / 65;
    const int j = p - q * 65;
    const int t = t0 + q;
    const int st = min(max(t - WS_ / 2, 0), T_ - WS_);
    const int base = st - smin;
    const bool isdep = (j == 64);
    const int widx = isdep ? nk : (base + j);
    const bool masked = isdep && ((unsigned)(dep - st) < (unsigned)WS_);
    float s;
    if (masked) {
      s = -3.0e38f;
    } else {
      const float* kr = &Ks[widx][0];
      const float* qr = &Qs[q][0];
      float dot = 0.f;
      #pragma unroll
      for (int d4 = 0; d4 < HD_ / 4; ++d4) {
        const float4 kv = *(const float4*)(kr + d4 * 4);
        const float4 qv = *(const float4*)(qr + d4 * 4);
        dot = fmaf(kv.x, qv.x, dot); dot = fmaf(kv.y, qv.y, dot);
        dot = fmaf(kv.z, qv.z, dot); dot = fmaf(kv.w, qv.w, dot);
      }
      const float dd = cw[widx] - cq[q];
      s = dot * SCALE_ - dd * dd * (1.0f / TAU_);
    }
    sc[q][j] = s;
  }
  __syncthreads();

  const int wv = tid >> 6, lane = tid & 63;
  for (int qi = 0; qi < QT_ / 4; ++qi) {
    const int q = wv * (QT_ / 4) + qi;
    const float v = sc[q][lane];
    float m = v;
    #pragma unroll
    for (int o = 32; o > 0; o >>= 1) m = fmaxf(m, __shfl_xor(m, o));
    const float sdep = sc[q][64];
    m = fmaxf(m, sdep);
    const float e = expf(v - m);
    float sum = e;
    #pragma unroll
    for (int o = 32; o > 0; o >>= 1) sum += __shfl_xor(sum, o);
    const float edep = expf(sdep - m);
    sum += edep;
    const float inv = 1.0f / sum;
    sc[q][lane] = e * inv;
    if (lane == 0) sc[q][64] = edep * inv;
  }
  __syncthreads();

  for (int p = tid; p < QT_ * HD_; p += 256) {
    const int q = p >> 7, d = p & 127;
    const int t = t0 + q;
    const int st = min(max(t - WS_ / 2, 0), T_ - WS_);
    const float* vbase = V + baseBH + d;
    float acc = 0.f;
    #pragma unroll 8
    for (int j = 0; j < WS_; ++j) {
      acc = fmaf(sc[q][j], vbase[(size_t)(st + j) * E_], acc);
    }
    acc = fmaf(sc[q][64], vbase[(size_t)dep * E_], acc);
    BfPair pr = f2bf_pair(acc);
    CTXhi[baseBH + (size_t)t * E_ + d] = pr.hi;
    CTXlo[baseBH + (size_t)t * E_ + d] = pr.lo;
  }
}

// ---------------------------------------------------------------------------
// Kernel 5: depot attends to the full sequence; overwrites ctx depot row.
// ---------------------------------------------------------------------------
__global__ __launch_bounds__(256) void attn_depot_kernel(
    const float* __restrict__ Q, const float* __restrict__ K,
    const float* __restrict__ V, const float* __restrict__ c_s,
    const int* __restrict__ depot, short* __restrict__ CTXhi,
    short* __restrict__ CTXlo) {
  __shared__ float qd[HD_];
  __shared__ float sc[T_];
  __shared__ float red[4];
  __shared__ float par[2][HD_];

  const int h = blockIdx.x % H_, b = blockIdx.x / H_;
  const int tid = threadIdx.x;
  const int wv = tid >> 6, lane = tid & 63;
  const int dep = depot[b];
  const size_t baseBH = ((size_t)b * T_) * E_ + (size_t)h * HD_;

  if (tid < HD_) qd[tid] = Q[baseBH + (size_t)dep * E_ + tid];
  __syncthreads();
  const float cdep = c_s[b * T_ + dep];

  for (int k = wv; k < T_; k += 4) {
    const float* krow = K + baseBH + (size_t)k * E_;
    float part = fmaf(qd[lane], krow[lane], qd[lane + 64] * krow[lane + 64]);
    #pragma unroll
    for (int o = 32; o > 0; o >>= 1) part += __shfl_xor(part, o);
    if (lane == 0) {
      const float dd = c_s[b * T_ + k] - cdep;
      sc[k] = part * SCALE_ - dd * dd * (1.0f / TAU_);
    }
  }
  __syncthreads();

  float lm = -3.0e38f;
  for (int k = tid; k < T_; k += 256) lm = fmaxf(lm, sc[k]);
  #pragma unroll
  for (int o = 32; o > 0; o >>= 1) lm = fmaxf(lm, __shfl_xor(lm, o));
  if (lane == 0) red[wv] = lm;
  __syncthreads();
  const float M = fmaxf(fmaxf(red[0], red[1]), fmaxf(red[2], red[3]));
  __syncthreads();
  float ls = 0.f;
  for (int k = tid; k < T_; k += 256) {
    const float e = expf(sc[k] - M);
    sc[k] = e;
    ls += e;
  }
  #pragma unroll
  for (int o = 32; o > 0; o >>= 1) ls += __shfl_xor(ls, o);
  if (lane == 0) red[wv] = ls;
  __syncthreads();
  const float inv = 1.0f / (red[0] + red[1] + red[2] + red[3]);
  __syncthreads();

  const int kg = tid >> 7, d = tid & 127;
  const float* vbase = V + baseBH + d;
  float acc = 0.f;
  #pragma unroll 8
  for (int k = kg * 512; k < kg * 512 + 512; ++k) {
    acc = fmaf(sc[k], vbase[(size_t)k * E_], acc);
  }
  par[kg][d] = acc * inv;
  __syncthreads();
  if (tid < HD_) {
    BfPair pr = f2bf_pair(par[0][tid] + par[1][tid]);
    CTXhi[baseBH + (size_t)dep * E_ + tid] = pr.hi;
    CTXlo[baseBH + (size_t)dep * E_ + tid] = pr.lo;
  }
}

// ---------------------------------------------------------------------------
extern "C" void kernel_launch(void* const* d_in, const int* in_sizes, int n_in,
                              void* d_out, int out_size, void* d_ws, size_t ws_size,
                              hipStream_t stream) {
  const float* h     = (const float*)d_in[0];
  const float* coord = (const float*)d_in[1];
  const float* Wq    = (const float*)d_in[2];
  const float* Wqb   = (const float*)d_in[3];
  const float* Wk    = (const float*)d_in[4];
  const float* Wkb   = (const float*)d_in[5];
  const float* Wv    = (const float*)d_in[6];
  const float* Wvb   = (const float*)d_in[7];
  const float* Wo    = (const float*)d_in[8];
  const float* Wob   = (const float*)d_in[9];
  float* out = (float*)d_out;

  char* ws = (char*)d_ws;
  const size_t MATF = (size_t)BB_ * T_ * E_ * 4;  // 8 MB fp32
  const size_t MATB = (size_t)BB_ * T_ * E_ * 2;  // 4 MB bf16
  const size_t WB   = (size_t)E_ * E_ * 2;        // 2 MB bf16
  size_t off = 0;
  float* Qb  = (float*)(ws + off); off += MATF;
  float* Kb  = (float*)(ws + off); off += MATF;
  float* Vb  = (float*)(ws + off); off += MATF;
  short* Ahi = (short*)(ws + off); off += MATB;
  short* Alo = (short*)(ws + off); off += MATB;
  short* CThi = (short*)(ws + off); off += MATB;
  short* CTlo = (short*)(ws + off); off += MATB;
  short* Whi[4], *Wlo[4];
  for (int i = 0; i < 4; ++i) { Whi[i] = (short*)(ws + off); off += WB; }
  for (int i = 0; i < 4; ++i) { Wlo[i] = (short*)(ws + off); off += WB; }
  float* c_s = (float*)(ws + off); off += (size_t)BB_ * T_ * 4;
  int* sidx  = (int*)(ws + off);   off += (size_t)BB_ * T_ * 4;
  int* depo  = (int*)(ws + off);

  // 1. stable sort by coordinate
  sort_rank_kernel<<<BB_, 256, 0, stream>>>(coord, sidx, c_s, depo);

  // 2a. gather + split h
  convert_gather_h<<<BB_ * T_, 256, 0, stream>>>(h, sidx, Ahi, Alo);

  // 2b. split weights
  WConv wc;
  wc.src[0] = Wq; wc.src[1] = Wk; wc.src[2] = Wv; wc.src[3] = Wo;
  for (int i = 0; i < 4; ++i) { wc.hi[i] = Whi[i]; wc.lo[i] = Wlo[i]; }
  convert_w_kernel<<<dim3(E_ * E_ / 1024, 1, 4), 256, 0, stream>>>(wc);

  // 3. QKV projections (bf16x3 MFMA, grid.z selects Q/K/V)
  GemmArgs qa;
  qa.Whi[0] = Whi[0]; qa.Whi[1] = Whi[1]; qa.Whi[2] = Whi[2];
  qa.Wlo[0] = Wlo[0]; qa.Wlo[1] = Wlo[1]; qa.Wlo[2] = Wlo[2];
  qa.bias[0] = Wqb; qa.bias[1] = Wkb; qa.bias[2] = Wvb;
  qa.C[0] = Qb; qa.C[1] = Kb; qa.C[2] = Vb;
  gemm_bf16x3<128, 64, 0><<<dim3(E_ / 128, (BB_ * T_) / 128, 3), 256, 0, stream>>>(
      qa, Ahi, Alo, sidx);

  // 4. sliding-window attention -> ctx (bf16-split)
  attn_local_kernel<<<BB_ * H_ * (T_ / QT_), 256, 0, stream>>>(
      Qb, Kb, Vb, c_s, depo, CThi, CTlo);

  // 5. depot full attention (overwrites ctx depot rows)
  attn_depot_kernel<<<BB_ * H_, 256, 0, stream>>>(
      Qb, Kb, Vb, c_s, depo, CThi, CTlo);

  // 6. output projection with fused un-sort scatter
  GemmArgs oa;
  oa.Whi[0] = Whi[3]; oa.Whi[1] = Whi[3]; oa.Whi[2] = Whi[3];
  oa.Wlo[0] = Wlo[3]; oa.Wlo[1] = Wlo[3]; oa.Wlo[2] = Wlo[3];
  oa.bias[0] = Wob; oa.bias[1] = Wob; oa.bias[2] = Wob;
  oa.C[0] = out; oa.C[1] = out; oa.C[2] = out;
  gemm_bf16x3<64, 32, 1><<<dim3(E_ / 128, (BB_ * T_) / 64, 1), 256, 0, stream>>>(
      oa, CThi, CTlo, sidx);
}

// Round 4
// 363.298 us; speedup vs baseline: 2.0605x; 1.4650x over previous
//
#include <hip/hip_runtime.h>
#include <hip/hip_bf16.h>
#include <cmath>

// Problem constants (match reference)
constexpr int BB_ = 2;
constexpr int T_  = 1024;
constexpr int E_  = 1024;
constexpr int H_  = 8;
constexpr int HD_ = 128;
constexpr int WS_ = 64;
constexpr float TAU_   = 10.0f;
constexpr float SCALE_ = 0.08838834764831843f;  // 1/sqrt(128)

typedef __attribute__((ext_vector_type(8))) short short8;
typedef __attribute__((ext_vector_type(4))) short shortx4;
typedef __attribute__((ext_vector_type(4))) float floatx4;

// Split fp32 -> bf16 hi + bf16 lo (RNE both). x ~= hi + lo to ~2^-17 rel.
struct BfPair { short hi, lo; };
__device__ inline BfPair f2bf_pair(float x) {
  union { float f; unsigned u; } a; a.f = x;
  unsigned rh = (a.u + 0x7FFFu + ((a.u >> 16) & 1u)) >> 16;
  union { unsigned u; float f; } hf; hf.u = rh << 16;
  union { float f; unsigned u; } b; b.f = x - hf.f;
  unsigned rl = (b.u + 0x7FFFu + ((b.u >> 16) & 1u)) >> 16;
  BfPair r; r.hi = (short)rh; r.lo = (short)rl; return r;
}

// ---------------------------------------------------------------------------
// Kernel 1: exact stable argsort via rank counting (T=1024 per batch).
// ---------------------------------------------------------------------------
__global__ __launch_bounds__(256) void sort_rank_kernel(
    const float* __restrict__ coord, int* __restrict__ sidx,
    float* __restrict__ c_s, int* __restrict__ depot) {
  __shared__ float c[T_];
  const int b = blockIdx.x;
  const float* cb = coord + (size_t)b * T_;
  for (int i = threadIdx.x; i < T_; i += 256) c[i] = cb[i];
  __syncthreads();
  for (int t = threadIdx.x; t < T_; t += 256) {
    const float ct = c[t];
    int rank = 0;
    #pragma unroll 8
    for (int u = 0; u < T_; ++u) {
      const float cu = c[u];
      rank += (cu < ct) || (cu == ct && u < t);
    }
    sidx[b * T_ + rank] = t;
    c_s[b * T_ + rank] = ct;
    if (t == 0) depot[b] = rank;
  }
}

// ---------------------------------------------------------------------------
// Kernel 2a: gather (h -> h_s) fused with fp32 -> bf16 hi/lo split.
// ---------------------------------------------------------------------------
__global__ __launch_bounds__(256) void convert_gather_h(
    const float* __restrict__ h, const int* __restrict__ sidx,
    short* __restrict__ Ahi, short* __restrict__ Alo) {
  const int gr = blockIdx.x;  // 0..B*T-1 (sorted domain)
  const int srow = (gr & ~(T_ - 1)) + sidx[gr];
  const float4 v = *(const float4*)(h + (size_t)srow * E_ + threadIdx.x * 4);
  shortx4 hv, lv;
  BfPair p0 = f2bf_pair(v.x), p1 = f2bf_pair(v.y);
  BfPair p2 = f2bf_pair(v.z), p3 = f2bf_pair(v.w);
  hv.x = p0.hi; hv.y = p1.hi; hv.z = p2.hi; hv.w = p3.hi;
  lv.x = p0.lo; lv.y = p1.lo; lv.z = p2.lo; lv.w = p3.lo;
  const size_t o = (size_t)gr * E_ + threadIdx.x * 4;
  *(shortx4*)(Ahi + o) = hv;
  *(shortx4*)(Alo + o) = lv;
}

// ---------------------------------------------------------------------------
// Kernel 2b: weight fp32 -> bf16 hi/lo split (4 matrices via grid.z).
// ---------------------------------------------------------------------------
struct WConv {
  const float* src[4];
  short* hi[4];
  short* lo[4];
};

__global__ __launch_bounds__(256) void convert_w_kernel(WConv a) {
  const int z = blockIdx.z;
  const size_t idx = ((size_t)blockIdx.x * 256 + threadIdx.x) * 4;
  const float4 v = *(const float4*)(a.src[z] + idx);
  shortx4 hv, lv;
  BfPair p0 = f2bf_pair(v.x), p1 = f2bf_pair(v.y);
  BfPair p2 = f2bf_pair(v.z), p3 = f2bf_pair(v.w);
  hv.x = p0.hi; hv.y = p1.hi; hv.z = p2.hi; hv.w = p3.hi;
  lv.x = p0.lo; lv.y = p1.lo; lv.z = p2.lo; lv.w = p3.lo;
  *(shortx4*)(a.hi[z] + idx) = hv;
  *(shortx4*)(a.lo[z] + idx) = lv;
}

// ---------------------------------------------------------------------------
// Kernel 3: bf16x3 split-precision MFMA GEMM.  (unchanged from R3 — passed)
// ---------------------------------------------------------------------------
struct GemmArgs {
  const short* Whi[3];
  const short* Wlo[3];
  const float* bias[3];
  float* C[3];
};

constexpr int LP_ = 56;  // padded LDS row stride (shorts)

template <int BM, int WM, int SCATTER>
__global__ __launch_bounds__(256, 2) void gemm_bf16x3(
    GemmArgs args, const short* __restrict__ Ahi, const short* __restrict__ Alo,
    const int* __restrict__ sidx) {
  constexpr int TMI = WM / 16;
  const short* __restrict__ Whi = args.Whi[blockIdx.z];
  const short* __restrict__ Wlo = args.Wlo[blockIdx.z];
  const float* __restrict__ bias = args.bias[blockIdx.z];
  float* __restrict__ C = args.C[blockIdx.z];

  __shared__ short As_hi[BM][LP_], As_lo[BM][LP_];
  __shared__ short Bs_hi[128][LP_], Bs_lo[128][LP_];

  const int tid = threadIdx.x;
  const int wv = tid >> 6, lane = tid & 63;
  const int kq = lane >> 4, ln15 = lane & 15;
  const int wm0 = (wv >> 1) * WM, wn0 = (wv & 1) * 64;
  const int m0 = blockIdx.y * BM, n0 = blockIdx.x * 128;

  floatx4 acc[TMI][4];
  #pragma unroll
  for (int i = 0; i < TMI; ++i)
    #pragma unroll
    for (int j = 0; j < 4; ++j) acc[i][j] = (floatx4){0.f, 0.f, 0.f, 0.f};

  for (int k0 = 0; k0 < E_; k0 += 32) {
    #pragma unroll
    for (int i = 0; i < BM * 4 / 256; ++i) {
      const int idx = tid + 256 * i;
      const int r = idx >> 2, c = idx & 3;
      const size_t g = (size_t)(m0 + r) * E_ + k0 + c * 8;
      *(short8*)&As_hi[r][c * 8] = *(const short8*)(Ahi + g);
      *(short8*)&As_lo[r][c * 8] = *(const short8*)(Alo + g);
    }
    #pragma unroll
    for (int i = 0; i < 2; ++i) {
      const int idx = tid + 256 * i;
      const int r = idx >> 2, c = idx & 3;
      const size_t g = (size_t)(n0 + r) * E_ + k0 + c * 8;
      *(short8*)&Bs_hi[r][c * 8] = *(const short8*)(Whi + g);
      *(short8*)&Bs_lo[r][c * 8] = *(const short8*)(Wlo + g);
    }
    __syncthreads();

    short8 ah[TMI], al[TMI], bh[4], bl[4];
    #pragma unroll
    for (int mi = 0; mi < TMI; ++mi) {
      ah[mi] = *(const short8*)&As_hi[wm0 + mi * 16 + ln15][kq * 8];
      al[mi] = *(const short8*)&As_lo[wm0 + mi * 16 + ln15][kq * 8];
    }
    #pragma unroll
    for (int ni = 0; ni < 4; ++ni) {
      bh[ni] = *(const short8*)&Bs_hi[wn0 + ni * 16 + ln15][kq * 8];
      bl[ni] = *(const short8*)&Bs_lo[wn0 + ni * 16 + ln15][kq * 8];
    }
    #pragma unroll
    for (int mi = 0; mi < TMI; ++mi)
      #pragma unroll
      for (int ni = 0; ni < 4; ++ni) {
        acc[mi][ni] = __builtin_amdgcn_mfma_f32_16x16x32_bf16(
            ah[mi], bh[ni], acc[mi][ni], 0, 0, 0);
        acc[mi][ni] = __builtin_amdgcn_mfma_f32_16x16x32_bf16(
            ah[mi], bl[ni], acc[mi][ni], 0, 0, 0);
        acc[mi][ni] = __builtin_amdgcn_mfma_f32_16x16x32_bf16(
            al[mi], bh[ni], acc[mi][ni], 0, 0, 0);
      }
    __syncthreads();
  }

  #pragma unroll
  for (int ni = 0; ni < 4; ++ni) {
    const int col = n0 + wn0 + ni * 16 + ln15;
    const float bv = bias[col];
    #pragma unroll
    for (int mi = 0; mi < TMI; ++mi) {
      #pragma unroll
      for (int r = 0; r < 4; ++r) {
        const int m = m0 + wm0 + mi * 16 + kq * 4 + r;
        const int orow = SCATTER ? ((m & ~(T_ - 1)) + sidx[m]) : m;
        C[(size_t)orow * E_ + col] = acc[mi][ni][r] + bv;
      }
    }
  }
}

// ---------------------------------------------------------------------------
// Kernel 4: local sliding-window attention (unchanged from R3 — passed).
// ---------------------------------------------------------------------------
constexpr int QT_ = 16;
constexpr int MAXR_ = 80;
constexpr int RPAD_ = 132;

__global__ __launch_bounds__(256) void attn_local_kernel(
    const float* __restrict__ Q, const float* __restrict__ K,
    const float* __restrict__ V, const float* __restrict__ c_s,
    const int* __restrict__ depot, short* __restrict__ CTXhi,
    short* __restrict__ CTXlo) {
  __shared__ float Ks[MAXR_][RPAD_];
  __shared__ float Qs[QT_][RPAD_];
  __shared__ float sc[QT_][68];
  __shared__ float cw[MAXR_];
  __shared__ float cq[QT_];

  const int tid = threadIdx.x;
  const int ntq = T_ / QT_;
  const int tq = blockIdx.x % ntq;
  const int bh = blockIdx.x / ntq;
  const int h = bh % H_, b = bh / H_;
  const int t0 = tq * QT_;
  const int dep = depot[b];

  const int smin = min(max(t0 - WS_ / 2, 0), T_ - WS_);
  const int smax = min(max(t0 + QT_ - 1 - WS_ / 2, 0), T_ - WS_);
  const int nk = smax + WS_ - smin;
  const int nrow = nk + 1;

  const size_t baseBH = ((size_t)b * T_) * E_ + (size_t)h * HD_;

  const int nf4 = nrow * (HD_ / 4);
  for (int i4 = tid; i4 < nf4; i4 += 256) {
    const int r = i4 >> 5, c4 = i4 & 31;
    const int key = (r < nk) ? (smin + r) : dep;
    const float4 kv = *(const float4*)(K + baseBH + (size_t)key * E_ + c4 * 4);
    *(float4*)&Ks[r][c4 * 4] = kv;
  }
  for (int r = tid; r < nrow; r += 256) {
    const int key = (r < nk) ? (smin + r) : dep;
    cw[r] = c_s[b * T_ + key];
  }
  for (int i4 = tid; i4 < QT_ * (HD_ / 4); i4 += 256) {
    const int r = i4 >> 5, c4 = i4 & 31;
    const float4 qv = *(const float4*)(Q + baseBH + (size_t)(t0 + r) * E_ + c4 * 4);
    *(float4*)&Qs[r][c4 * 4] = qv;
  }
  if (tid < QT_) cq[tid] = c_s[b * T_ + t0 + tid];
  __syncthreads();

  for (int p = tid; p < QT_ * 65; p += 256) {
    const int q = p / 65;
    const int j = p - q * 65;
    const int t = t0 + q;
    const int st = min(max(t - WS_ / 2, 0), T_ - WS_);
    const int base = st - smin;
    const bool isdep = (j == 64);
    const int widx = isdep ? nk : (base + j);
    const bool masked = isdep && ((unsigned)(dep - st) < (unsigned)WS_);
    float s;
    if (masked) {
      s = -3.0e38f;
    } else {
      const float* kr = &Ks[widx][0];
      const float* qr = &Qs[q][0];
      float dot = 0.f;
      #pragma unroll
      for (int d4 = 0; d4 < HD_ / 4; ++d4) {
        const float4 kv = *(const float4*)(kr + d4 * 4);
        const float4 qv = *(const float4*)(qr + d4 * 4);
        dot = fmaf(kv.x, qv.x, dot); dot = fmaf(kv.y, qv.y, dot);
        dot = fmaf(kv.z, qv.z, dot); dot = fmaf(kv.w, qv.w, dot);
      }
      const float dd = cw[widx] - cq[q];
      s = dot * SCALE_ - dd * dd * (1.0f / TAU_);
    }
    sc[q][j] = s;
  }
  __syncthreads();

  const int wv = tid >> 6, lane = tid & 63;
  for (int qi = 0; qi < QT_ / 4; ++qi) {
    const int q = wv * (QT_ / 4) + qi;
    const float v = sc[q][lane];
    float m = v;
    #pragma unroll
    for (int o = 32; o > 0; o >>= 1) m = fmaxf(m, __shfl_xor(m, o));
    const float sdep = sc[q][64];
    m = fmaxf(m, sdep);
    const float e = expf(v - m);
    float sum = e;
    #pragma unroll
    for (int o = 32; o > 0; o >>= 1) sum += __shfl_xor(sum, o);
    const float edep = expf(sdep - m);
    sum += edep;
    const float inv = 1.0f / sum;
    sc[q][lane] = e * inv;
    if (lane == 0) sc[q][64] = edep * inv;
  }
  __syncthreads();

  for (int p = tid; p < QT_ * HD_; p += 256) {
    const int q = p >> 7, d = p & 127;
    const int t = t0 + q;
    const int st = min(max(t - WS_ / 2, 0), T_ - WS_);
    const float* vbase = V + baseBH + d;
    float acc = 0.f;
    #pragma unroll 8
    for (int j = 0; j < WS_; ++j) {
      acc = fmaf(sc[q][j], vbase[(size_t)(st + j) * E_], acc);
    }
    acc = fmaf(sc[q][64], vbase[(size_t)dep * E_], acc);
    BfPair pr = f2bf_pair(acc);
    CTXhi[baseBH + (size_t)t * E_ + d] = pr.hi;
    CTXlo[baseBH + (size_t)t * E_ + d] = pr.lo;
  }
}

// ---------------------------------------------------------------------------
// Depot attention, grid-parallel (was 16 blocks / 203 us, occupancy 0.67%).
// Phase 1: scores.  grid = B*H*DCH_ blocks, 64 keys/block, wave-per-key.
// ---------------------------------------------------------------------------
constexpr int DCH_ = 16;   // score chunks per (b,h) -> 256 blocks
constexpr int VSP_ = 8;    // ctx K-splits per (b,h)  -> 128 blocks

__global__ __launch_bounds__(256) void depot_scores_kernel(
    const float* __restrict__ Q, const float* __restrict__ K,
    const float* __restrict__ c_s, const int* __restrict__ depot,
    float* __restrict__ scg) {
  const int chunk = blockIdx.x % DCH_;
  const int bh = blockIdx.x / DCH_;
  const int h = bh % H_, b = bh / H_;
  const int tid = threadIdx.x, wv = tid >> 6, lane = tid & 63;
  const int dep = depot[b];
  const size_t baseBH = ((size_t)b * T_) * E_ + (size_t)h * HD_;
  __shared__ float qd[HD_];
  if (tid < HD_) qd[tid] = Q[baseBH + (size_t)dep * E_ + tid];
  __syncthreads();
  const float cdep = c_s[b * T_ + dep];
  constexpr int KPB = T_ / DCH_;       // 64 keys per block
  const int k0 = chunk * KPB + wv * (KPB / 4);
  #pragma unroll 4
  for (int i = 0; i < KPB / 4; ++i) {  // 16 iterations per wave
    const int k = k0 + i;
    const float* krow = K + baseBH + (size_t)k * E_;
    float part = fmaf(qd[lane], krow[lane], qd[lane + 64] * krow[lane + 64]);
    #pragma unroll
    for (int o = 32; o > 0; o >>= 1) part += __shfl_xor(part, o);
    if (lane == 0) {
      const float dd = c_s[b * T_ + k] - cdep;
      scg[bh * T_ + k] = part * SCALE_ - dd * dd * (1.0f / TAU_);
    }
  }
}

// Phase 2: softmax over T per (b,h). 16 tiny blocks.
__global__ __launch_bounds__(256) void depot_softmax_kernel(
    float* __restrict__ scg) {
  __shared__ float sc[T_];
  __shared__ float red[4];
  const int bh = blockIdx.x;
  const int tid = threadIdx.x, wv = tid >> 6, lane = tid & 63;
  float* s = scg + bh * T_;
  float lm = -3.0e38f;
  for (int k = tid; k < T_; k += 256) { sc[k] = s[k]; lm = fmaxf(lm, sc[k]); }
  #pragma unroll
  for (int o = 32; o > 0; o >>= 1) lm = fmaxf(lm, __shfl_xor(lm, o));
  if (lane == 0) red[wv] = lm;
  __syncthreads();
  const float M = fmaxf(fmaxf(red[0], red[1]), fmaxf(red[2], red[3]));
  __syncthreads();
  float ls = 0.f;
  float ev[T_ / 256];
  #pragma unroll
  for (int i = 0; i < T_ / 256; ++i) {
    ev[i] = expf(sc[tid + 256 * i] - M);
    ls += ev[i];
  }
  #pragma unroll
  for (int o = 32; o > 0; o >>= 1) ls += __shfl_xor(ls, o);
  if (lane == 0) red[wv] = ls;
  __syncthreads();
  const float inv = 1.0f / (red[0] + red[1] + red[2] + red[3]);
  #pragma unroll
  for (int i = 0; i < T_ / 256; ++i) s[tid + 256 * i] = ev[i] * inv;
}

// Phase 3: ctx partials. grid = B*H*VSP_; each block 128 keys x 128 dims.
__global__ __launch_bounds__(256) void depot_ctx_kernel(
    const float* __restrict__ V, const float* __restrict__ scg,
    float* __restrict__ part) {
  __shared__ float par[2][HD_];
  const int sp = blockIdx.x % VSP_;
  const int bh = blockIdx.x / VSP_;
  const int h = bh % H_, b = bh / H_;
  const int tid = threadIdx.x;
  const int d = tid & 127, kg = tid >> 7;
  const size_t baseBH = ((size_t)b * T_) * E_ + (size_t)h * HD_;
  constexpr int KPB = T_ / VSP_;           // 128 keys per block
  const int k0 = sp * KPB + kg * (KPB / 2);
  const float* vbase = V + baseBH + d;
  const float* a = scg + bh * T_;
  float acc = 0.f;
  #pragma unroll 8
  for (int k = k0; k < k0 + KPB / 2; ++k) {
    acc = fmaf(a[k], vbase[(size_t)k * E_], acc);
  }
  par[kg][d] = acc;
  __syncthreads();
  if (tid < HD_) part[((size_t)sp * BB_ * H_ + bh) * HD_ + tid] =
      par[0][tid] + par[1][tid];
}

// Phase 4: reduce splits, bf16-split, write depot ctx rows. 1 block.
__global__ __launch_bounds__(256) void depot_write_kernel(
    const float* __restrict__ part, const int* __restrict__ depot,
    short* __restrict__ CTXhi, short* __restrict__ CTXlo) {
  for (int o = threadIdx.x; o < BB_ * H_ * HD_; o += 256) {
    const int bh = o >> 7, d = o & 127;
    float s = 0.f;
    #pragma unroll
    for (int sp = 0; sp < VSP_; ++sp)
      s += part[((size_t)sp * BB_ * H_ + bh) * HD_ + d];
    const int h = bh % H_, b = bh / H_;
    const int dep = depot[b];
    BfPair pr = f2bf_pair(s);
    const size_t idx = ((size_t)b * T_ + dep) * E_ + (size_t)h * HD_ + d;
    CTXhi[idx] = pr.hi;
    CTXlo[idx] = pr.lo;
  }
}

// ---------------------------------------------------------------------------
extern "C" void kernel_launch(void* const* d_in, const int* in_sizes, int n_in,
                              void* d_out, int out_size, void* d_ws, size_t ws_size,
                              hipStream_t stream) {
  const float* h     = (const float*)d_in[0];
  const float* coord = (const float*)d_in[1];
  const float* Wq    = (const float*)d_in[2];
  const float* Wqb   = (const float*)d_in[3];
  const float* Wk    = (const float*)d_in[4];
  const float* Wkb   = (const float*)d_in[5];
  const float* Wv    = (const float*)d_in[6];
  const float* Wvb   = (const float*)d_in[7];
  const float* Wo    = (const float*)d_in[8];
  const float* Wob   = (const float*)d_in[9];
  float* out = (float*)d_out;

  char* ws = (char*)d_ws;
  const size_t MATF = (size_t)BB_ * T_ * E_ * 4;  // 8 MB fp32
  const size_t MATB = (size_t)BB_ * T_ * E_ * 2;  // 4 MB bf16
  const size_t WB   = (size_t)E_ * E_ * 2;        // 2 MB bf16
  size_t off = 0;
  float* Qb  = (float*)(ws + off); off += MATF;
  float* Kb  = (float*)(ws + off); off += MATF;
  float* Vb  = (float*)(ws + off); off += MATF;
  short* Ahi = (short*)(ws + off); off += MATB;
  short* Alo = (short*)(ws + off); off += MATB;
  short* CThi = (short*)(ws + off); off += MATB;
  short* CTlo = (short*)(ws + off); off += MATB;
  short* Whi[4], *Wlo[4];
  for (int i = 0; i < 4; ++i) { Whi[i] = (short*)(ws + off); off += WB; }
  for (int i = 0; i < 4; ++i) { Wlo[i] = (short*)(ws + off); off += WB; }
  float* c_s = (float*)(ws + off); off += (size_t)BB_ * T_ * 4;
  int* sidx  = (int*)(ws + off);   off += (size_t)BB_ * T_ * 4;
  int* depo  = (int*)(ws + off);   off += 256;  // padded
  float* scg  = (float*)(ws + off); off += (size_t)BB_ * H_ * T_ * 4;   // 64 KB
  float* dpar = (float*)(ws + off); off += (size_t)VSP_ * BB_ * H_ * HD_ * 4;

  // 1. stable sort by coordinate
  sort_rank_kernel<<<BB_, 256, 0, stream>>>(coord, sidx, c_s, depo);

  // 2a. gather + split h
  convert_gather_h<<<BB_ * T_, 256, 0, stream>>>(h, sidx, Ahi, Alo);

  // 2b. split weights
  WConv wc;
  wc.src[0] = Wq; wc.src[1] = Wk; wc.src[2] = Wv; wc.src[3] = Wo;
  for (int i = 0; i < 4; ++i) { wc.hi[i] = Whi[i]; wc.lo[i] = Wlo[i]; }
  convert_w_kernel<<<dim3(E_ * E_ / 1024, 1, 4), 256, 0, stream>>>(wc);

  // 3. QKV projections (bf16x3 MFMA, grid.z selects Q/K/V)
  GemmArgs qa;
  qa.Whi[0] = Whi[0]; qa.Whi[1] = Whi[1]; qa.Whi[2] = Whi[2];
  qa.Wlo[0] = Wlo[0]; qa.Wlo[1] = Wlo[1]; qa.Wlo[2] = Wlo[2];
  qa.bias[0] = Wqb; qa.bias[1] = Wkb; qa.bias[2] = Wvb;
  qa.C[0] = Qb; qa.C[1] = Kb; qa.C[2] = Vb;
  gemm_bf16x3<128, 64, 0><<<dim3(E_ / 128, (BB_ * T_) / 128, 3), 256, 0, stream>>>(
      qa, Ahi, Alo, sidx);

  // 4. sliding-window attention -> ctx (bf16-split)
  attn_local_kernel<<<BB_ * H_ * (T_ / QT_), 256, 0, stream>>>(
      Qb, Kb, Vb, c_s, depo, CThi, CTlo);

  // 5. depot full attention, grid-parallel (overwrites ctx depot rows)
  depot_scores_kernel<<<BB_ * H_ * DCH_, 256, 0, stream>>>(
      Qb, Kb, c_s, depo, scg);
  depot_softmax_kernel<<<BB_ * H_, 256, 0, stream>>>(scg);
  depot_ctx_kernel<<<BB_ * H_ * VSP_, 256, 0, stream>>>(Vb, scg, dpar);
  depot_write_kernel<<<1, 256, 0, stream>>>(dpar, depo, CThi, CTlo);

  // 6. output projection with fused un-sort scatter
  GemmArgs oa;
  oa.Whi[0] = Whi[3]; oa.Whi[1] = Whi[3]; oa.Whi[2] = Whi[3];
  oa.Wlo[0] = Wlo[3]; oa.Wlo[1] = Wlo[3]; oa.Wlo[2] = Wlo[3];
  oa.bias[0] = Wob; oa.bias[1] = Wob; oa.bias[2] = Wob;
  oa.C[0] = out; oa.C[1] = out; oa.C[2] = out;
  gemm_bf16x3<64, 32, 1><<<dim3(E_ / 128, (BB_ * T_) / 64, 1), 256, 0, stream>>>(
      oa, CThi, CTlo, sidx);
}

// Round 5
// 268.065 us; speedup vs baseline: 2.7925x; 1.3553x over previous
//
#include <hip/hip_runtime.h>
#include <hip/hip_bf16.h>
#include <cmath>

// Problem constants (match reference)
constexpr int BB_ = 2;
constexpr int T_  = 1024;
constexpr int E_  = 1024;
constexpr int H_  = 8;
constexpr int HD_ = 128;
constexpr int WS_ = 64;
constexpr float TAU_   = 10.0f;
constexpr float SCALE_ = 0.08838834764831843f;  // 1/sqrt(128)

typedef __attribute__((ext_vector_type(8))) short short8;
typedef __attribute__((ext_vector_type(4))) short shortx4;
typedef __attribute__((ext_vector_type(4))) float floatx4;

// Split fp32 -> bf16 hi + bf16 lo (RNE both). x ~= hi + lo to ~2^-17 rel.
struct BfPair { short hi, lo; };
__device__ inline BfPair f2bf_pair(float x) {
  union { float f; unsigned u; } a; a.f = x;
  unsigned rh = (a.u + 0x7FFFu + ((a.u >> 16) & 1u)) >> 16;
  union { unsigned u; float f; } hf; hf.u = rh << 16;
  union { float f; unsigned u; } b; b.f = x - hf.f;
  unsigned rl = (b.u + 0x7FFFu + ((b.u >> 16) & 1u)) >> 16;
  BfPair r; r.hi = (short)rh; r.lo = (short)rl; return r;
}

// ---------------------------------------------------------------------------
// Kernel 1: exact stable argsort via rank counting, grid-parallel.
// Was 2 blocks / 101 us (occupancy 0.09%). Now B*(T/16)=128 blocks; each block
// stages c[] in LDS, handles 16 t-values; thread (tl,ch) scans u-chunk of 64
// for t=t0+tl; 16-lane shfl tree sums partial ranks.
// rank[t] = #{u : c[u]<c[t] or (c[u]==c[t] and u<t)}  == stable sort rank.
// ---------------------------------------------------------------------------
constexpr int STB_ = 16;  // t-values per block

__global__ __launch_bounds__(256) void sort_rank_kernel(
    const float* __restrict__ coord, int* __restrict__ sidx,
    float* __restrict__ c_s, int* __restrict__ depot) {
  __shared__ float c[T_];
  const int nb = T_ / STB_;                    // 64 blocks per batch
  const int b = blockIdx.x / nb;
  const int t0 = (blockIdx.x % nb) * STB_;
  const float* cb = coord + (size_t)b * T_;
  for (int i = threadIdx.x; i < T_; i += 256) c[i] = cb[i];
  __syncthreads();
  const int tl = threadIdx.x >> 4;             // 0..15: which t
  const int ch = threadIdx.x & 15;             // 0..15: which u-chunk
  const int t = t0 + tl;
  const float ct = c[t];
  int rank = 0;
  const int u0 = ch * (T_ / 16);
  #pragma unroll 8
  for (int i = 0; i < T_ / 16; ++i) {          // 64 compares
    const int u = u0 + i;
    const float cu = c[u];
    rank += (cu < ct) || (cu == ct && u < t);
  }
  // sum the 16 chunk-partials (consecutive 16 lanes of one wave)
  #pragma unroll
  for (int o = 8; o > 0; o >>= 1) rank += __shfl_xor(rank, o);
  if (ch == 0) {
    sidx[b * T_ + rank] = t;
    c_s[b * T_ + rank] = ct;
    if (t == 0) depot[b] = rank;
  }
}

// ---------------------------------------------------------------------------
// Kernel 2a: gather (h -> h_s) fused with fp32 -> bf16 hi/lo split.
// ---------------------------------------------------------------------------
__global__ __launch_bounds__(256) void convert_gather_h(
    const float* __restrict__ h, const int* __restrict__ sidx,
    short* __restrict__ Ahi, short* __restrict__ Alo) {
  const int gr = blockIdx.x;  // 0..B*T-1 (sorted domain)
  const int srow = (gr & ~(T_ - 1)) + sidx[gr];
  const float4 v = *(const float4*)(h + (size_t)srow * E_ + threadIdx.x * 4);
  shortx4 hv, lv;
  BfPair p0 = f2bf_pair(v.x), p1 = f2bf_pair(v.y);
  BfPair p2 = f2bf_pair(v.z), p3 = f2bf_pair(v.w);
  hv.x = p0.hi; hv.y = p1.hi; hv.z = p2.hi; hv.w = p3.hi;
  lv.x = p0.lo; lv.y = p1.lo; lv.z = p2.lo; lv.w = p3.lo;
  const size_t o = (size_t)gr * E_ + threadIdx.x * 4;
  *(shortx4*)(Ahi + o) = hv;
  *(shortx4*)(Alo + o) = lv;
}

// ---------------------------------------------------------------------------
// Kernel 2b: weight fp32 -> bf16 hi/lo split (4 matrices via grid.z).
// ---------------------------------------------------------------------------
struct WConv {
  const float* src[4];
  short* hi[4];
  short* lo[4];
};

__global__ __launch_bounds__(256) void convert_w_kernel(WConv a) {
  const int z = blockIdx.z;
  const size_t idx = ((size_t)blockIdx.x * 256 + threadIdx.x) * 4;
  const float4 v = *(const float4*)(a.src[z] + idx);
  shortx4 hv, lv;
  BfPair p0 = f2bf_pair(v.x), p1 = f2bf_pair(v.y);
  BfPair p2 = f2bf_pair(v.z), p3 = f2bf_pair(v.w);
  hv.x = p0.hi; hv.y = p1.hi; hv.z = p2.hi; hv.w = p3.hi;
  lv.x = p0.lo; lv.y = p1.lo; lv.z = p2.lo; lv.w = p3.lo;
  *(shortx4*)(a.hi[z] + idx) = hv;
  *(shortx4*)(a.lo[z] + idx) = lv;
}

// ---------------------------------------------------------------------------
// Kernel 3: bf16x3 split-precision MFMA GEMM.  (unchanged — passed)
// ---------------------------------------------------------------------------
struct GemmArgs {
  const short* Whi[3];
  const short* Wlo[3];
  const float* bias[3];
  float* C[3];
};

constexpr int LP_ = 56;  // padded LDS row stride (shorts)

template <int BM, int WM, int SCATTER>
__global__ __launch_bounds__(256, 2) void gemm_bf16x3(
    GemmArgs args, const short* __restrict__ Ahi, const short* __restrict__ Alo,
    const int* __restrict__ sidx) {
  constexpr int TMI = WM / 16;
  const short* __restrict__ Whi = args.Whi[blockIdx.z];
  const short* __restrict__ Wlo = args.Wlo[blockIdx.z];
  const float* __restrict__ bias = args.bias[blockIdx.z];
  float* __restrict__ C = args.C[blockIdx.z];

  __shared__ short As_hi[BM][LP_], As_lo[BM][LP_];
  __shared__ short Bs_hi[128][LP_], Bs_lo[128][LP_];

  const int tid = threadIdx.x;
  const int wv = tid >> 6, lane = tid & 63;
  const int kq = lane >> 4, ln15 = lane & 15;
  const int wm0 = (wv >> 1) * WM, wn0 = (wv & 1) * 64;
  const int m0 = blockIdx.y * BM, n0 = blockIdx.x * 128;

  floatx4 acc[TMI][4];
  #pragma unroll
  for (int i = 0; i < TMI; ++i)
    #pragma unroll
    for (int j = 0; j < 4; ++j) acc[i][j] = (floatx4){0.f, 0.f, 0.f, 0.f};

  for (int k0 = 0; k0 < E_; k0 += 32) {
    #pragma unroll
    for (int i = 0; i < BM * 4 / 256; ++i) {
      const int idx = tid + 256 * i;
      const int r = idx >> 2, c = idx & 3;
      const size_t g = (size_t)(m0 + r) * E_ + k0 + c * 8;
      *(short8*)&As_hi[r][c * 8] = *(const short8*)(Ahi + g);
      *(short8*)&As_lo[r][c * 8] = *(const short8*)(Alo + g);
    }
    #pragma unroll
    for (int i = 0; i < 2; ++i) {
      const int idx = tid + 256 * i;
      const int r = idx >> 2, c = idx & 3;
      const size_t g = (size_t)(n0 + r) * E_ + k0 + c * 8;
      *(short8*)&Bs_hi[r][c * 8] = *(const short8*)(Whi + g);
      *(short8*)&Bs_lo[r][c * 8] = *(const short8*)(Wlo + g);
    }
    __syncthreads();

    short8 ah[TMI], al[TMI], bh[4], bl[4];
    #pragma unroll
    for (int mi = 0; mi < TMI; ++mi) {
      ah[mi] = *(const short8*)&As_hi[wm0 + mi * 16 + ln15][kq * 8];
      al[mi] = *(const short8*)&As_lo[wm0 + mi * 16 + ln15][kq * 8];
    }
    #pragma unroll
    for (int ni = 0; ni < 4; ++ni) {
      bh[ni] = *(const short8*)&Bs_hi[wn0 + ni * 16 + ln15][kq * 8];
      bl[ni] = *(const short8*)&Bs_lo[wn0 + ni * 16 + ln15][kq * 8];
    }
    #pragma unroll
    for (int mi = 0; mi < TMI; ++mi)
      #pragma unroll
      for (int ni = 0; ni < 4; ++ni) {
        acc[mi][ni] = __builtin_amdgcn_mfma_f32_16x16x32_bf16(
            ah[mi], bh[ni], acc[mi][ni], 0, 0, 0);
        acc[mi][ni] = __builtin_amdgcn_mfma_f32_16x16x32_bf16(
            ah[mi], bl[ni], acc[mi][ni], 0, 0, 0);
        acc[mi][ni] = __builtin_amdgcn_mfma_f32_16x16x32_bf16(
            al[mi], bh[ni], acc[mi][ni], 0, 0, 0);
      }
    __syncthreads();
  }

  #pragma unroll
  for (int ni = 0; ni < 4; ++ni) {
    const int col = n0 + wn0 + ni * 16 + ln15;
    const float bv = bias[col];
    #pragma unroll
    for (int mi = 0; mi < TMI; ++mi) {
      #pragma unroll
      for (int r = 0; r < 4; ++r) {
        const int m = m0 + wm0 + mi * 16 + kq * 4 + r;
        const int orow = SCATTER ? ((m & ~(T_ - 1)) + sidx[m]) : m;
        C[(size_t)orow * E_ + col] = acc[mi][ni][r] + bv;
      }
    }
  }
}

// ---------------------------------------------------------------------------
// Kernel 4: local sliding-window attention (unchanged — passed).
// ---------------------------------------------------------------------------
constexpr int QT_ = 16;
constexpr int MAXR_ = 80;
constexpr int RPAD_ = 132;

__global__ __launch_bounds__(256) void attn_local_kernel(
    const float* __restrict__ Q, const float* __restrict__ K,
    const float* __restrict__ V, const float* __restrict__ c_s,
    const int* __restrict__ depot, short* __restrict__ CTXhi,
    short* __restrict__ CTXlo) {
  __shared__ float Ks[MAXR_][RPAD_];
  __shared__ float Qs[QT_][RPAD_];
  __shared__ float sc[QT_][68];
  __shared__ float cw[MAXR_];
  __shared__ float cq[QT_];

  const int tid = threadIdx.x;
  const int ntq = T_ / QT_;
  const int tq = blockIdx.x % ntq;
  const int bh = blockIdx.x / ntq;
  const int h = bh % H_, b = bh / H_;
  const int t0 = tq * QT_;
  const int dep = depot[b];

  const int smin = min(max(t0 - WS_ / 2, 0), T_ - WS_);
  const int smax = min(max(t0 + QT_ - 1 - WS_ / 2, 0), T_ - WS_);
  const int nk = smax + WS_ - smin;
  const int nrow = nk + 1;

  const size_t baseBH = ((size_t)b * T_) * E_ + (size_t)h * HD_;

  const int nf4 = nrow * (HD_ / 4);
  for (int i4 = tid; i4 < nf4; i4 += 256) {
    const int r = i4 >> 5, c4 = i4 & 31;
    const int key = (r < nk) ? (smin + r) : dep;
    const float4 kv = *(const float4*)(K + baseBH + (size_t)key * E_ + c4 * 4);
    *(float4*)&Ks[r][c4 * 4] = kv;
  }
  for (int r = tid; r < nrow; r += 256) {
    const int key = (r < nk) ? (smin + r) : dep;
    cw[r] = c_s[b * T_ + key];
  }
  for (int i4 = tid; i4 < QT_ * (HD_ / 4); i4 += 256) {
    const int r = i4 >> 5, c4 = i4 & 31;
    const float4 qv = *(const float4*)(Q + baseBH + (size_t)(t0 + r) * E_ + c4 * 4);
    *(float4*)&Qs[r][c4 * 4] = qv;
  }
  if (tid < QT_) cq[tid] = c_s[b * T_ + t0 + tid];
  __syncthreads();

  for (int p = tid; p < QT_ * 65; p += 256) {
    const int q = p / 65;
    const int j = p - q * 65;
    const int t = t0 + q;
    const int st = min(max(t - WS_ / 2, 0), T_ - WS_);
    const int base = st - smin;
    const bool isdep = (j == 64);
    const int widx = isdep ? nk : (base + j);
    const bool masked = isdep && ((unsigned)(dep - st) < (unsigned)WS_);
    float s;
    if (masked) {
      s = -3.0e38f;
    } else {
      const float* kr = &Ks[widx][0];
      const float* qr = &Qs[q][0];
      float dot = 0.f;
      #pragma unroll
      for (int d4 = 0; d4 < HD_ / 4; ++d4) {
        const float4 kv = *(const float4*)(kr + d4 * 4);
        const float4 qv = *(const float4*)(qr + d4 * 4);
        dot = fmaf(kv.x, qv.x, dot); dot = fmaf(kv.y, qv.y, dot);
        dot = fmaf(kv.z, qv.z, dot); dot = fmaf(kv.w, qv.w, dot);
      }
      const float dd = cw[widx] - cq[q];
      s = dot * SCALE_ - dd * dd * (1.0f / TAU_);
    }
    sc[q][j] = s;
  }
  __syncthreads();

  const int wv = tid >> 6, lane = tid & 63;
  for (int qi = 0; qi < QT_ / 4; ++qi) {
    const int q = wv * (QT_ / 4) + qi;
    const float v = sc[q][lane];
    float m = v;
    #pragma unroll
    for (int o = 32; o > 0; o >>= 1) m = fmaxf(m, __shfl_xor(m, o));
    const float sdep = sc[q][64];
    m = fmaxf(m, sdep);
    const float e = expf(v - m);
    float sum = e;
    #pragma unroll
    for (int o = 32; o > 0; o >>= 1) sum += __shfl_xor(sum, o);
    const float edep = expf(sdep - m);
    sum += edep;
    const float inv = 1.0f / sum;
    sc[q][lane] = e * inv;
    if (lane == 0) sc[q][64] = edep * inv;
  }
  __syncthreads();

  for (int p = tid; p < QT_ * HD_; p += 256) {
    const int q = p >> 7, d = p & 127;
    const int t = t0 + q;
    const int st = min(max(t - WS_ / 2, 0), T_ - WS_);
    const float* vbase = V + baseBH + d;
    float acc = 0.f;
    #pragma unroll 8
    for (int j = 0; j < WS_; ++j) {
      acc = fmaf(sc[q][j], vbase[(size_t)(st + j) * E_], acc);
    }
    acc = fmaf(sc[q][64], vbase[(size_t)dep * E_], acc);
    BfPair pr = f2bf_pair(acc);
    CTXhi[baseBH + (size_t)t * E_ + d] = pr.hi;
    CTXlo[baseBH + (size_t)t * E_ + d] = pr.lo;
  }
}

// ---------------------------------------------------------------------------
// Depot attention, grid-parallel (unchanged — passed).
// ---------------------------------------------------------------------------
constexpr int DCH_ = 16;   // score chunks per (b,h) -> 256 blocks
constexpr int VSP_ = 8;    // ctx K-splits per (b,h)  -> 128 blocks

__global__ __launch_bounds__(256) void depot_scores_kernel(
    const float* __restrict__ Q, const float* __restrict__ K,
    const float* __restrict__ c_s, const int* __restrict__ depot,
    float* __restrict__ scg) {
  const int chunk = blockIdx.x % DCH_;
  const int bh = blockIdx.x / DCH_;
  const int h = bh % H_, b = bh / H_;
  const int tid = threadIdx.x, wv = tid >> 6, lane = tid & 63;
  const int dep = depot[b];
  const size_t baseBH = ((size_t)b * T_) * E_ + (size_t)h * HD_;
  __shared__ float qd[HD_];
  if (tid < HD_) qd[tid] = Q[baseBH + (size_t)dep * E_ + tid];
  __syncthreads();
  const float cdep = c_s[b * T_ + dep];
  constexpr int KPB = T_ / DCH_;       // 64 keys per block
  const int k0 = chunk * KPB + wv * (KPB / 4);
  #pragma unroll 4
  for (int i = 0; i < KPB / 4; ++i) {  // 16 iterations per wave
    const int k = k0 + i;
    const float* krow = K + baseBH + (size_t)k * E_;
    float part = fmaf(qd[lane], krow[lane], qd[lane + 64] * krow[lane + 64]);
    #pragma unroll
    for (int o = 32; o > 0; o >>= 1) part += __shfl_xor(part, o);
    if (lane == 0) {
      const float dd = c_s[b * T_ + k] - cdep;
      scg[bh * T_ + k] = part * SCALE_ - dd * dd * (1.0f / TAU_);
    }
  }
}

__global__ __launch_bounds__(256) void depot_softmax_kernel(
    float* __restrict__ scg) {
  __shared__ float sc[T_];
  __shared__ float red[4];
  const int bh = blockIdx.x;
  const int tid = threadIdx.x, wv = tid >> 6, lane = tid & 63;
  float* s = scg + bh * T_;
  float lm = -3.0e38f;
  for (int k = tid; k < T_; k += 256) { sc[k] = s[k]; lm = fmaxf(lm, sc[k]); }
  #pragma unroll
  for (int o = 32; o > 0; o >>= 1) lm = fmaxf(lm, __shfl_xor(lm, o));
  if (lane == 0) red[wv] = lm;
  __syncthreads();
  const float M = fmaxf(fmaxf(red[0], red[1]), fmaxf(red[2], red[3]));
  __syncthreads();
  float ls = 0.f;
  float ev[T_ / 256];
  #pragma unroll
  for (int i = 0; i < T_ / 256; ++i) {
    ev[i] = expf(sc[tid + 256 * i] - M);
    ls += ev[i];
  }
  #pragma unroll
  for (int o = 32; o > 0; o >>= 1) ls += __shfl_xor(ls, o);
  if (lane == 0) red[wv] = ls;
  __syncthreads();
  const float inv = 1.0f / (red[0] + red[1] + red[2] + red[3]);
  #pragma unroll
  for (int i = 0; i < T_ / 256; ++i) s[tid + 256 * i] = ev[i] * inv;
}

__global__ __launch_bounds__(256) void depot_ctx_kernel(
    const float* __restrict__ V, const float* __restrict__ scg,
    float* __restrict__ part) {
  __shared__ float par[2][HD_];
  const int sp = blockIdx.x % VSP_;
  const int bh = blockIdx.x / VSP_;
  const int h = bh % H_, b = bh / H_;
  const int tid = threadIdx.x;
  const int d = tid & 127, kg = tid >> 7;
  const size_t baseBH = ((size_t)b * T_) * E_ + (size_t)h * HD_;
  constexpr int KPB = T_ / VSP_;           // 128 keys per block
  const int k0 = sp * KPB + kg * (KPB / 2);
  const float* vbase = V + baseBH + d;
  const float* a = scg + bh * T_;
  float acc = 0.f;
  #pragma unroll 8
  for (int k = k0; k < k0 + KPB / 2; ++k) {
    acc = fmaf(a[k], vbase[(size_t)k * E_], acc);
  }
  par[kg][d] = acc;
  __syncthreads();
  if (tid < HD_) part[((size_t)sp * BB_ * H_ + bh) * HD_ + tid] =
      par[0][tid] + par[1][tid];
}

__global__ __launch_bounds__(256) void depot_write_kernel(
    const float* __restrict__ part, const int* __restrict__ depot,
    short* __restrict__ CTXhi, short* __restrict__ CTXlo) {
  for (int o = threadIdx.x; o < BB_ * H_ * HD_; o += 256) {
    const int bh = o >> 7, d = o & 127;
    float s = 0.f;
    #pragma unroll
    for (int sp = 0; sp < VSP_; ++sp)
      s += part[((size_t)sp * BB_ * H_ + bh) * HD_ + d];
    const int h = bh % H_, b = bh / H_;
    const int dep = depot[b];
    BfPair pr = f2bf_pair(s);
    const size_t idx = ((size_t)b * T_ + dep) * E_ + (size_t)h * HD_ + d;
    CTXhi[idx] = pr.hi;
    CTXlo[idx] = pr.lo;
  }
}

// ---------------------------------------------------------------------------
extern "C" void kernel_launch(void* const* d_in, const int* in_sizes, int n_in,
                              void* d_out, int out_size, void* d_ws, size_t ws_size,
                              hipStream_t stream) {
  const float* h     = (const float*)d_in[0];
  const float* coord = (const float*)d_in[1];
  const float* Wq    = (const float*)d_in[2];
  const float* Wqb   = (const float*)d_in[3];
  const float* Wk    = (const float*)d_in[4];
  const float* Wkb   = (const float*)d_in[5];
  const float* Wv    = (const float*)d_in[6];
  const float* Wvb   = (const float*)d_in[7];
  const float* Wo    = (const float*)d_in[8];
  const float* Wob   = (const float*)d_in[9];
  float* out = (float*)d_out;

  char* ws = (char*)d_ws;
  const size_t MATF = (size_t)BB_ * T_ * E_ * 4;  // 8 MB fp32
  const size_t MATB = (size_t)BB_ * T_ * E_ * 2;  // 4 MB bf16
  const size_t WB   = (size_t)E_ * E_ * 2;        // 2 MB bf16
  size_t off = 0;
  float* Qb  = (float*)(ws + off); off += MATF;
  float* Kb  = (float*)(ws + off); off += MATF;
  float* Vb  = (float*)(ws + off); off += MATF;
  short* Ahi = (short*)(ws + off); off += MATB;
  short* Alo = (short*)(ws + off); off += MATB;
  short* CThi = (short*)(ws + off); off += MATB;
  short* CTlo = (short*)(ws + off); off += MATB;
  short* Whi[4], *Wlo[4];
  for (int i = 0; i < 4; ++i) { Whi[i] = (short*)(ws + off); off += WB; }
  for (int i = 0; i < 4; ++i) { Wlo[i] = (short*)(ws + off); off += WB; }
  float* c_s = (float*)(ws + off); off += (size_t)BB_ * T_ * 4;
  int* sidx  = (int*)(ws + off);   off += (size_t)BB_ * T_ * 4;
  int* depo  = (int*)(ws + off);   off += 256;  // padded
  float* scg  = (float*)(ws + off); off += (size_t)BB_ * H_ * T_ * 4;   // 64 KB
  float* dpar = (float*)(ws + off); off += (size_t)VSP_ * BB_ * H_ * HD_ * 4;

  // 1. stable sort by coordinate (grid-parallel rank counting)
  sort_rank_kernel<<<BB_ * (T_ / STB_), 256, 0, stream>>>(coord, sidx, c_s, depo);

  // 2a. gather + split h
  convert_gather_h<<<BB_ * T_, 256, 0, stream>>>(h, sidx, Ahi, Alo);

  // 2b. split weights
  WConv wc;
  wc.src[0] = Wq; wc.src[1] = Wk; wc.src[2] = Wv; wc.src[3] = Wo;
  for (int i = 0; i < 4; ++i) { wc.hi[i] = Whi[i]; wc.lo[i] = Wlo[i]; }
  convert_w_kernel<<<dim3(E_ * E_ / 1024, 1, 4), 256, 0, stream>>>(wc);

  // 3. QKV projections (bf16x3 MFMA, grid.z selects Q/K/V)
  GemmArgs qa;
  qa.Whi[0] = Whi[0]; qa.Whi[1] = Whi[1]; qa.Whi[2] = Whi[2];
  qa.Wlo[0] = Wlo[0]; qa.Wlo[1] = Wlo[1]; qa.Wlo[2] = Wlo[2];
  qa.bias[0] = Wqb; qa.bias[1] = Wkb; qa.bias[2] = Wvb;
  qa.C[0] = Qb; qa.C[1] = Kb; qa.C[2] = Vb;
  gemm_bf16x3<128, 64, 0><<<dim3(E_ / 128, (BB_ * T_) / 128, 3), 256, 0, stream>>>(
      qa, Ahi, Alo, sidx);

  // 4. sliding-window attention -> ctx (bf16-split)
  attn_local_kernel<<<BB_ * H_ * (T_ / QT_), 256, 0, stream>>>(
      Qb, Kb, Vb, c_s, depo, CThi, CTlo);

  // 5. depot full attention, grid-parallel (overwrites ctx depot rows)
  depot_scores_kernel<<<BB_ * H_ * DCH_, 256, 0, stream>>>(
      Qb, Kb, c_s, depo, scg);
  depot_softmax_kernel<<<BB_ * H_, 256, 0, stream>>>(scg);
  depot_ctx_kernel<<<BB_ * H_ * VSP_, 256, 0, stream>>>(Vb, scg, dpar);
  depot_write_kernel<<<1, 256, 0, stream>>>(dpar, depo, CThi, CTlo);

  // 6. output projection with fused un-sort scatter
  GemmArgs oa;
  oa.Whi[0] = Whi[3]; oa.Whi[1] = Whi[3]; oa.Whi[2] = Whi[3];
  oa.Wlo[0] = Wlo[3]; oa.Wlo[1] = Wlo[3]; oa.Wlo[2] = Wlo[3];
  oa.bias[0] = Wob; oa.bias[1] = Wob; oa.bias[2] = Wob;
  oa.C[0] = out; oa.C[1] = out; oa.C[2] = out;
  gemm_bf16x3<64, 32, 1><<<dim3(E_ / 128, (BB_ * T_) / 64, 1), 256, 0, stream>>>(
      oa, CThi, CTlo, sidx);
}